// Round 3
// baseline (119.829 us; speedup 1.0000x reference)
//
#include <hip/hip_runtime.h>
#include <hip/hip_bf16.h>

// svPositionsAtT0: (B=64, N=63, 3)  f32
// svEncoding:      (B=64, N=63, 512) f32
// lengths:         (B=64,) i32
// out:             (B, 512, 28, 28) f32 = max(0, scatter-max of valid agent encodings)
#define NSV    63
#define HID    512
#define GW     28
#define GH     28
#define CELLS  (GW * GH)              // 784
#define HCHUNK 16                     // h-values per block
#define NTHREADS 256
#define TILE_F4 (HCHUNK * CELLS / 4)  // 3136 float4 per block tile
#define FULL_IT (TILE_F4 / NTHREADS)  // 12
#define REM     (TILE_F4 - FULL_IT * NTHREADS)  // 64

__global__ __launch_bounds__(NTHREADS)
void scatter_grid_kernel(const float* __restrict__ pos,
                         const float* __restrict__ enc,
                         const int*   __restrict__ lengths,
                         float*       __restrict__ out) {
    const int b      = blockIdx.y;
    const int h_base = blockIdx.x * HCHUNK;
    const int t      = threadIdx.x;

    __shared__ int                cell_s[NSV];      // per-agent cell (or -1)
    __shared__ float              enc_s[NSV * HCHUNK];
    __shared__ int                cnt_s;            // # unique touched cells
    __shared__ int                tcell_s[NSV];     // compact touched-cell list
    __shared__ unsigned long long tmask_s[NSV];     // agent bitmask per touched cell

    if (t == 0) cnt_s = 0;

    // ---- stage encoding slice: enc[b, n, h_base:h_base+16] ----
    {
        const int n = t >> 2;        // 0..63
        const int q = t & 3;
        if (n < NSV) {
            const float4 v = ((const float4*)(enc + ((size_t)b * NSV + n) * HID + h_base))[q];
            ((float4*)(enc_s + n * HCHUNK))[q] = v;
        }
    }

    // ---- per-agent cell index + validity ----
    if (t < NSV) {
        const float x = pos[((size_t)b * NSV + t) * 3 + 0];
        const float y = pos[((size_t)b * NSV + t) * 3 + 1];
        const int len = lengths[b];
        // exact replication of jnp: (x * 28) / 224 in f32, trunc toward zero
        const int xi = (int)(x * 28.0f / 224.0f);
        const int yi = (int)(y * 28.0f / 224.0f);
        int c = -1;
        if ((t < len) && (xi < GW) && (yi < GH)) {
            c = min(max(xi, 0), GW - 1) * GH + min(max(yi, 0), GH - 1);
        }
        cell_s[t] = c;
    }
    __syncthreads();

    // ---- dedup: first agent of each touched cell owns it, collects the bitmask ----
    if (t < NSV) {
        const int c = cell_s[t];
        if (c >= 0) {
            bool owner = true;
            for (int n = 0; n < t; ++n) owner &= (cell_s[n] != c);
            if (owner) {
                unsigned long long m = 0;
                for (int n = t; n < NSV; ++n)
                    if (cell_s[n] == c) m |= (1ull << n);
                const int i = atomicAdd(&cnt_s, 1);
                tcell_s[i] = c;
                tmask_s[i] = m;
            }
        }
    }

    // ---- Phase 1: branch-free zero-stream of the whole contiguous tile ----
    // out[b][h_base..h_base+16][0..784) is one contiguous 12544-float range.
    float4* d4 = (float4*)(out + ((size_t)b * HID + h_base) * CELLS);
    const float4 z = make_float4(0.f, 0.f, 0.f, 0.f);
    #pragma unroll
    for (int i = 0; i < FULL_IT; ++i) d4[t + i * NTHREADS] = z;
    if (t < REM) d4[t + FULL_IT * NTHREADS] = z;

    // Barrier: drains vmcnt(0) (phase-1 stores reach L2 in order) and makes
    // cnt_s / tcell_s / tmask_s visible to all threads.
    __syncthreads();

    // ---- Phase 2: overwrite the <=63*16 touched (cell, h) elements ----
    const int total = cnt_s * HCHUNK;
    for (int p = t; p < total; p += NTHREADS) {
        const int i = p >> 4;        // touched-cell index
        const int h = p & 15;
        unsigned long long m = tmask_s[i];
        float val = 0.f;             // grid init 0 -> implicit max with 0
        while (m) {
            const int n = __ffsll(m) - 1;
            m &= m - 1;
            val = fmaxf(val, enc_s[n * HCHUNK + h]);
        }
        out[((size_t)b * HID + h_base + h) * CELLS + tcell_s[i]] = val;
    }
}

extern "C" void kernel_launch(void* const* d_in, const int* in_sizes, int n_in,
                              void* d_out, int out_size, void* d_ws, size_t ws_size,
                              hipStream_t stream) {
    const float* pos     = (const float*)d_in[0];   // (B, 63, 3)
    const float* enc     = (const float*)d_in[1];   // (B, 63, 512)
    const int*   lengths = (const int*)d_in[2];     // (B,)
    float*       out     = (float*)d_out;           // (B, 512, 28, 28)

    const int B = in_sizes[2];                      // 64

    dim3 grid(HID / HCHUNK, B);                     // (32, 64) = 2048 blocks
    dim3 block(NTHREADS);
    scatter_grid_kernel<<<grid, block, 0, stream>>>(pos, enc, lengths, out);
}